// Round 10
// baseline (1991.519 us; speedup 1.0000x reference)
//
#include <hip/hip_runtime.h>
#include <hip/hip_bf16.h>
#include <math.h>

#define TT   512
#define CC   768
#define HH   12
#define HSZ  64
#define LL   12
#define C4   3072
#define BTOT 2048   // B*T
#define NQKV 2304   // 3*C
#define NX   ((long)BTOT * CC)

typedef __attribute__((ext_vector_type(8))) short short8;
typedef __attribute__((ext_vector_type(4))) float f32x4;

__device__ __forceinline__ unsigned short f2b_bits(float f) {
    unsigned u = __float_as_uint(f);
    return (unsigned short)((u + 0x7fffu + ((u >> 16) & 1u)) >> 16);
}

// async global->LDS, 16B per lane; LDS dest is wave-uniform base + lane*16B
__device__ __forceinline__ void gl_lds16(const void* g, void* l) {
    __builtin_amdgcn_global_load_lds(
        (const __attribute__((address_space(1))) unsigned int*)g,
        (__attribute__((address_space(3))) unsigned int*)l,
        16, 0, 0);
}

// ---------------------------------------------------------------- embedding
__global__ __launch_bounds__(256) void embed_k(const int* __restrict__ idx,
    const float* __restrict__ tok, const float* __restrict__ pos,
    float* __restrict__ x)
{
    int r   = blockIdx.x;
    int tid = threadIdx.x;
    int t   = r & (TT - 1);
    long id = idx[r];
    const float* te = tok + id * (long)CC;
    const float* pe = pos + (long)t * CC;
    float* xr = x + (long)r * CC;
#pragma unroll
    for (int i = 0; i < 3; ++i) {
        int c = tid + i * 256;
        xr[c] = te[c] + pe[c];
    }
}

// ---------------------------------------------------------------- layernorm (fp32 in, bf16 out)
__global__ __launch_bounds__(256) void ln_b(const float* __restrict__ x,
    const float* __restrict__ g, const float* __restrict__ b,
    __hip_bfloat16* __restrict__ y)
{
    int r = blockIdx.x, tid = threadIdx.x;
    const float* xr = x + (long)r * CC;
    float v[3];
    v[0] = xr[tid]; v[1] = xr[tid + 256]; v[2] = xr[tid + 512];
    float s  = v[0] + v[1] + v[2];
    float sq = v[0]*v[0] + v[1]*v[1] + v[2]*v[2];
#pragma unroll
    for (int off = 32; off > 0; off >>= 1) {
        s  += __shfl_down(s, off);
        sq += __shfl_down(sq, off);
    }
    __shared__ float ss[4], ssq[4];
    int w = tid >> 6;
    if ((tid & 63) == 0) { ss[w] = s; ssq[w] = sq; }
    __syncthreads();
    s  = ss[0] + ss[1] + ss[2] + ss[3];
    sq = ssq[0] + ssq[1] + ssq[2] + ssq[3];
    float mean = s * (1.0f / CC);
    float var  = sq * (1.0f / CC) - mean * mean;
    float rs   = rsqrtf(var + 1e-5f);
    __hip_bfloat16* yr = y + (long)r * CC;
#pragma unroll
    for (int i = 0; i < 3; ++i) {
        int c = tid + i * 256;
        yr[c] = __float2bfloat16((v[i] - mean) * rs * g[c] + b[c]);
    }
}

// ---------------------------------------- fused split-K reduce + residual + LN
// x[r] += p0[r]+p1[r]+p2[r]+p3[r] + bias; optionally y = LN(x; g,b) in bf16.
template <bool DOLN>
__global__ __launch_bounds__(256) void red_ln(float* __restrict__ x,
    const float* __restrict__ p, const float* __restrict__ bias,
    const float* __restrict__ g, const float* __restrict__ b,
    __hip_bfloat16* __restrict__ y)
{
    int r = blockIdx.x, tid = threadIdx.x;
    float* xr = x + (long)r * CC;
    const float* pr = p + (long)r * CC;
    float v[3];
#pragma unroll
    for (int i = 0; i < 3; ++i) {
        int c = tid + i * 256;
        float s = xr[c] + bias[c];
        s += pr[c];
        s += pr[c + 1 * NX];
        s += pr[c + 2 * NX];
        s += pr[c + 3 * NX];
        xr[c] = s;
        v[i] = s;
    }
    if (!DOLN) return;
    float s  = v[0] + v[1] + v[2];
    float sq = v[0]*v[0] + v[1]*v[1] + v[2]*v[2];
#pragma unroll
    for (int off = 32; off > 0; off >>= 1) {
        s  += __shfl_down(s, off);
        sq += __shfl_down(sq, off);
    }
    __shared__ float ss[4], ssq[4];
    int w = tid >> 6;
    if ((tid & 63) == 0) { ss[w] = s; ssq[w] = sq; }
    __syncthreads();
    s  = ss[0] + ss[1] + ss[2] + ss[3];
    sq = ssq[0] + ssq[1] + ssq[2] + ssq[3];
    float mean = s * (1.0f / CC);
    float var  = sq * (1.0f / CC) - mean * mean;
    float rs   = rsqrtf(var + 1e-5f);
    __hip_bfloat16* yr = y + (long)r * CC;
#pragma unroll
    for (int i = 0; i < 3; ++i) {
        int c = tid + i * 256;
        yr[c] = __float2bfloat16((v[i] - mean) * rs * g[c] + b[c]);
    }
}

// ------------------------------------------------- weight convert/transpose
// src fp32 [R][D] -> dst bf16 [D][R]; 64x64 tiles; grid (D/64, R/64, L)
__global__ __launch_bounds__(256) void cvtT_k(const float* __restrict__ src,
    __hip_bfloat16* __restrict__ dst, int R, int D, long sSrc, long sDst)
{
    src += (long)blockIdx.z * sSrc;
    dst += (long)blockIdx.z * sDst;
    __shared__ float t[64][65];
    int d0 = blockIdx.x * 64, r0 = blockIdx.y * 64;
    int tid = threadIdx.x;
#pragma unroll
    for (int i = 0; i < 4; ++i) {
        int flat = tid + i * 256;
        int r = flat >> 4, c4 = (flat & 15) * 4;
        float4 v = *(const float4*)&src[(long)(r0 + r) * D + d0 + c4];
        t[r][c4 + 0] = v.x; t[r][c4 + 1] = v.y;
        t[r][c4 + 2] = v.z; t[r][c4 + 3] = v.w;
    }
    __syncthreads();
#pragma unroll
    for (int i = 0; i < 4; ++i) {
        int flat = tid + i * 256;
        int n = flat >> 4, kq = (flat & 15) * 4;
        ushort4 o;
        o.x = f2b_bits(t[kq + 0][n]); o.y = f2b_bits(t[kq + 1][n]);
        o.z = f2b_bits(t[kq + 2][n]); o.w = f2b_bits(t[kq + 3][n]);
        *(ushort4*)&dst[(long)(d0 + n) * R + r0 + kq] = o;
    }
}

// Wq/Wk/Wv [L][h][768][64] -> qkvT_all [L][2304][768]; grid (12, 36, L)
__global__ __launch_bounds__(256) void cvt_qkvT(const float* __restrict__ Wq,
    const float* __restrict__ Wk, const float* __restrict__ Wv,
    __hip_bfloat16* __restrict__ out)
{
    int c0 = blockIdx.x * 64;
    int g  = blockIdx.y;
    int l  = blockIdx.z;
    int which = g / 12, h = g % 12;
    const long wAtt = (long)HH * CC * HSZ;
    const float* src = (which == 0 ? Wq : which == 1 ? Wk : Wv)
                       + l * wAtt + (long)h * CC * HSZ;   // [768][64]
    __hip_bfloat16* dst = out + (long)l * NQKV * CC + (long)(which * CC + h * HSZ) * CC;
    __shared__ float t[64][65];
    int tid = threadIdx.x;
#pragma unroll
    for (int i = 0; i < 4; ++i) {
        int flat = tid + i * 256;
        int r = flat >> 4, c4 = (flat & 15) * 4;
        float4 v = *(const float4*)&src[(long)(c0 + r) * HSZ + c4];
        t[r][c4 + 0] = v.x; t[r][c4 + 1] = v.y;
        t[r][c4 + 2] = v.z; t[r][c4 + 3] = v.w;
    }
    __syncthreads();
#pragma unroll
    for (int i = 0; i < 4; ++i) {
        int flat = tid + i * 256;
        int n = flat >> 4, kq = (flat & 15) * 4;
        ushort4 o;
        o.x = f2b_bits(t[kq + 0][n]); o.y = f2b_bits(t[kq + 1][n]);
        o.z = f2b_bits(t[kq + 2][n]); o.w = f2b_bits(t[kq + 3][n]);
        *(ushort4*)&dst[(long)n * CC + c0 + kq] = o;
    }
}

// ---------------------------------------------------------------- bf16 MFMA GEMM
// C[M,N] = A[M,K] @ B[K,N]; A bf16 [M][lda], BT bf16 [N][ldb] (=B^T); K%32==0,
// K/32 >= 3. Tile 64 x 128, BK=32, 4 waves (2x2), each wave 32x64 out.
// Depth-4 pipeline: 4 LDS buffers, 3 tiles in flight via global_load_lds,
// counted s_waitcnt vmcnt(N) + raw s_barrier (never drains to 0 mid-loop).
// EPI 1: QKV (cols<1536 -> Cb, cols>=1536 -> Vt transposed);
// EPI 2: +bias exact-GELU -> bf16;
// EPI 5: split-K over blockIdx.z: store fp32 partial to Cf + sk*NX (no bias).
template <int EPI>
__global__ __launch_bounds__(256, 3) void gemm_bf16(
    const __hip_bfloat16* __restrict__ A,
    const __hip_bfloat16* __restrict__ BT,
    __hip_bfloat16* __restrict__ Cb, float* __restrict__ Cf,
    const float* __restrict__ bias, __hip_bfloat16* __restrict__ Vt,
    int K, int lda, int ldb, int ldc)
{
    __shared__ short Asm[4][64 * 32];
    __shared__ short Bsm[4][128 * 32];
    const int tid  = threadIdx.x;
    const int lane = tid & 63;
    const int wid  = tid >> 6;
    const int wm = wid >> 1, wn = wid & 1;
    const int row0 = blockIdx.y * 64, col0 = blockIdx.x * 128;
    const int sk = (EPI == 5) ? blockIdx.z : 0;

    const int gr = tid >> 2;               // staging row 0..63
    // swizzled source column-block: cb = (pos + (row>>1)) & 3
    const int cb = ((tid & 3) + (tid >> 3)) & 3;
    const int gk = cb * 8;                 // k offset in shorts
    const __hip_bfloat16* Ap = A  + (long)(row0 + gr) * lda + sk * K + gk;
    const __hip_bfloat16* Bp = BT + (long)(col0 + gr) * ldb + sk * K + gk;
    const int lofs = wid * 512;            // per-wave LDS segment (shorts)

    f32x4 acc[2][4] = {};
    const int fr = lane & 15, g = lane >> 4;

    // swizzled read offsets (shorts), fixed per lane: row*32 + ((g-(row>>1))&3)*8
    int offA[2], offB[4];
#pragma unroll
    for (int m = 0; m < 2; ++m) {
        int row = wm * 32 + m * 16 + fr;
        offA[m] = row * 32 + (((g - (row >> 1)) & 3) * 8);
    }
#pragma unroll
    for (int n = 0; n < 4; ++n) {
        int row = wn * 64 + n * 16 + fr;
        offB[n] = row * 32 + (((g - (row >> 1)) & 3) * 8);
    }

#define STAGE(buf)                                                          \
    do {                                                                    \
        gl_lds16(Ap, &Asm[buf][lofs]);                                      \
        gl_lds16(Bp, &Bsm[buf][lofs]);                                      \
        gl_lds16(Bp + (long)64 * ldb, &Bsm[buf][lofs + 64 * 32]);           \
        Ap += 32; Bp += 32;                                                 \
    } while (0)

    // prologue: tiles 0,1,2 in flight (3 loads each)
    STAGE(0); STAGE(1); STAGE(2);

    const int nt = K >> 5;                 // >= 3
    for (int t = 0; t < nt; ++t) {
        if (t < nt - 2)       asm volatile("s_waitcnt vmcnt(6)" ::: "memory");
        else if (t == nt - 2) asm volatile("s_waitcnt vmcnt(3)" ::: "memory");
        else                  asm volatile("s_waitcnt vmcnt(0)" ::: "memory");
        __builtin_amdgcn_s_barrier();      // all waves' tile-t loads resident;
        __builtin_amdgcn_sched_barrier(0); // also fences reuse of buf[(t+3)&3]
        if (t + 3 < nt) STAGE((t + 3) & 3);

        const int cur = t & 3;
        short8 af[2], bf[4];
#pragma unroll
        for (int m = 0; m < 2; ++m)
            af[m] = *(const short8*)&Asm[cur][offA[m]];
#pragma unroll
        for (int n = 0; n < 4; ++n)
            bf[n] = *(const short8*)&Bsm[cur][offB[n]];
#pragma unroll
        for (int m = 0; m < 2; ++m)
#pragma unroll
            for (int n = 0; n < 4; ++n)
                acc[m][n] = __builtin_amdgcn_mfma_f32_16x16x32_bf16(
                    af[m], bf[n], acc[m][n], 0, 0, 0);
    }
#undef STAGE

    const int fq = lane >> 4;
    float* pout = (EPI == 5) ? (Cf + (long)sk * NX) : nullptr;
#pragma unroll
    for (int m = 0; m < 2; ++m) {
        int rbase = row0 + wm * 32 + m * 16 + fq * 4;
#pragma unroll
        for (int n = 0; n < 4; ++n) {
            int col = col0 + wn * 64 + n * 16 + fr;
            if (EPI == 1 && col >= 1536) {
                int hd = col - 1536;
                int b = rbase >> 9, t = rbase & (TT - 1);
                ushort4 o;
                o.x = f2b_bits(acc[m][n][0]); o.y = f2b_bits(acc[m][n][1]);
                o.z = f2b_bits(acc[m][n][2]); o.w = f2b_bits(acc[m][n][3]);
                *(ushort4*)&Vt[((long)(b * HH + (hd >> 6)) * HSZ + (hd & 63)) * TT + t] = o;
                continue;
            }
            float bv = (EPI == 2) ? bias[col] : 0.f;
#pragma unroll
            for (int j = 0; j < 4; ++j) {
                long row = rbase + j;
                float v = acc[m][n][j];
                if (EPI == 1) {
                    Cb[row * ldc + col] = __float2bfloat16(v);
                } else if (EPI == 2) {
                    v += bv;
                    v = 0.5f * v * (1.0f + erff(v * 0.70710678118654752f));
                    Cb[row * ldc + col] = __float2bfloat16(v);
                } else { // EPI == 5
                    pout[row * ldc + col] = v;
                }
            }
        }
    }
}

// ------------------------------------- fused attention + proj + residual + LN2
// Block = (qt, b): 12 waves, one per head, 16 queries. Each wave: flash attn
// (S^T = mfma(K,Q), wave-private P/corr/l in LDS, no barriers — DS ops are
// per-wave in-order), o -> o_lds[16][776]. Then block-level proj GEMM
// (o_lds @ WoT streamed from L2), residual into x, cross-wave LN -> xn bf16.
__global__ __launch_bounds__(768) void attn_proj(
    const __hip_bfloat16* __restrict__ qkv,
    const __hip_bfloat16* __restrict__ vT,
    const __hip_bfloat16* __restrict__ woT,
    const float* __restrict__ bo,
    const float* __restrict__ g2, const float* __restrict__ bb2,
    float* __restrict__ x, __hip_bfloat16* __restrict__ xn)
{
    const int qt = blockIdx.x;
    const int b  = blockIdx.y;
    const int tid = threadIdx.x;
    const int wid = tid >> 6;          // head 0..11
    const int lane = tid & 63;
    const int h = wid;
    const int t0 = qt * 16;
    const int fr = lane & 15, g = lane >> 4;

    __shared__ unsigned short o_lds[16][776];       // padded: bank-safe
    __shared__ unsigned short P_all[12][16 * 40];
    __shared__ float corr_all[12][16], l_all[12][16];
    __shared__ float sum_w[12][16], sq_w[12][16];
    __shared__ float mean_s[16], rs_s[16];

    unsigned short* P_w = P_all[wid];

    // ---------------- attention (per-wave, barrier-free) ----------------
    const long qbase = ((long)(b * TT + t0 + fr)) * NQKV + h * HSZ + g * 8;
    short8 qf0 = *(const short8*)(qkv + qbase);
    short8 qf1 = *(const short8*)(qkv + qbase + 32);

    f32x4 oacc[4] = {};
    float m_run = -3.0e38f, l_run = 0.f;
    const int t_lane = t0 + fr;
    const int smax = t0 + 15;
    const long kcol = CC + h * HSZ + g * 8;
    const long vrow = (((long)(b * HH + h) * HSZ) + fr) * TT + g * 8;

    short8 ka0, ka1, ka2, ka3;
    {
        long kb0 = ((long)(b * TT + fr)) * NQKV + kcol;
        long kb1 = ((long)(b * TT + 16 + fr)) * NQKV + kcol;
        ka0 = *(const short8*)(qkv + kb0);
        ka1 = *(const short8*)(qkv + kb0 + 32);
        ka2 = *(const short8*)(qkv + kb1);
        ka3 = *(const short8*)(qkv + kb1 + 32);
    }

    for (int s0 = 0; s0 <= smax; s0 += 32) {
        f32x4 st0 = {}, st1 = {};
        st0 = __builtin_amdgcn_mfma_f32_16x16x32_bf16(ka0, qf0, st0, 0, 0, 0);
        st0 = __builtin_amdgcn_mfma_f32_16x16x32_bf16(ka1, qf1, st0, 0, 0, 0);
        st1 = __builtin_amdgcn_mfma_f32_16x16x32_bf16(ka2, qf0, st1, 0, 0, 0);
        st1 = __builtin_amdgcn_mfma_f32_16x16x32_bf16(ka3, qf1, st1, 0, 0, 0);

        const bool more = (s0 + 32 <= smax);
        short8 kn0, kn1, kn2, kn3;
        if (more) {
            long kb0 = ((long)(b * TT + s0 + 32 + fr)) * NQKV + kcol;
            long kb1 = ((long)(b * TT + s0 + 48 + fr)) * NQKV + kcol;
            kn0 = *(const short8*)(qkv + kb0);
            kn1 = *(const short8*)(qkv + kb0 + 32);
            kn2 = *(const short8*)(qkv + kb1);
            kn3 = *(const short8*)(qkv + kb1 + 32);
        }
        short8 vc0 = *(const short8*)(vT + vrow + s0);
        short8 vc1 = *(const short8*)(vT + vrow + 16 * TT + s0);
        short8 vc2 = *(const short8*)(vT + vrow + 32 * TT + s0);
        short8 vc3 = *(const short8*)(vT + vrow + 48 * TT + s0);

        float p[8];
        float mx = -3.0e38f;
#pragma unroll
        for (int j = 0; j < 4; ++j) {
            int s = s0 + g * 4 + j;
            float v = st0[j] * 0.125f;
            v = (s <= t_lane) ? v : -3.0e38f;
            p[j] = v; mx = fmaxf(mx, v);
        }
#pragma unroll
        for (int j = 0; j < 4; ++j) {
            int s = s0 + 16 + g * 4 + j;
            float v = st1[j] * 0.125f;
            v = (s <= t_lane) ? v : -3.0e38f;
            p[4 + j] = v; mx = fmaxf(mx, v);
        }
        mx = fmaxf(mx, __shfl_xor(mx, 16));
        mx = fmaxf(mx, __shfl_xor(mx, 32));
        float mnew = fmaxf(m_run, mx);
        float corr = __expf(m_run - mnew);
        float psum = 0.f;
#pragma unroll
        for (int i = 0; i < 8; ++i) {
            float e = __expf(p[i] - mnew);
            p[i] = e; psum += e;
        }
        psum += __shfl_xor(psum, 16);
        psum += __shfl_xor(psum, 32);
        l_run = l_run * corr + psum;
        m_run = mnew;

        if (lane < 16) corr_all[wid][lane] = corr;
        unsigned u0 = (unsigned)f2b_bits(p[0]) | ((unsigned)f2b_bits(p[1]) << 16);
        unsigned u1 = (unsigned)f2b_bits(p[2]) | ((unsigned)f2b_bits(p[3]) << 16);
        unsigned u2 = (unsigned)f2b_bits(p[4]) | ((unsigned)f2b_bits(p[5]) << 16);
        unsigned u3 = (unsigned)f2b_bits(p[6]) | ((unsigned)f2b_bits(p[7]) << 16);
        *(unsigned*)&P_w[fr * 40 + g * 4]          = u0;
        *(unsigned*)&P_w[fr * 40 + g * 4 + 2]      = u1;
        *(unsigned*)&P_w[fr * 40 + 16 + g * 4]     = u2;
        *(unsigned*)&P_w[fr * 40 + 16 + g * 4 + 2] = u3;
        __builtin_amdgcn_sched_barrier(0);   // keep DS writes before DS reads

        float cr0 = corr_all[wid][g * 4 + 0], cr1 = corr_all[wid][g * 4 + 1];
        float cr2 = corr_all[wid][g * 4 + 2], cr3 = corr_all[wid][g * 4 + 3];
        short8 pf = *(const short8*)&P_w[fr * 40 + g * 8];
        oacc[0][0] *= cr0; oacc[0][1] *= cr1; oacc[0][2] *= cr2; oacc[0][3] *= cr3;
        oacc[0] = __builtin_amdgcn_mfma_f32_16x16x32_bf16(pf, vc0, oacc[0], 0, 0, 0);
        oacc[1][0] *= cr0; oacc[1][1] *= cr1; oacc[1][2] *= cr2; oacc[1][3] *= cr3;
        oacc[1] = __builtin_amdgcn_mfma_f32_16x16x32_bf16(pf, vc1, oacc[1], 0, 0, 0);
        oacc[2][0] *= cr0; oacc[2][1] *= cr1; oacc[2][2] *= cr2; oacc[2][3] *= cr3;
        oacc[2] = __builtin_amdgcn_mfma_f32_16x16x32_bf16(pf, vc2, oacc[2], 0, 0, 0);
        oacc[3][0] *= cr0; oacc[3][1] *= cr1; oacc[3][2] *= cr2; oacc[3][3] *= cr3;
        oacc[3] = __builtin_amdgcn_mfma_f32_16x16x32_bf16(pf, vc3, oacc[3], 0, 0, 0);

        if (more) { ka0 = kn0; ka1 = kn1; ka2 = kn2; ka3 = kn3; }
    }

    if (lane < 16) l_all[wid][lane] = l_run;
    __builtin_amdgcn_sched_barrier(0);
    {
        float il0 = 1.f / l_all[wid][g * 4 + 0];
        float il1 = 1.f / l_all[wid][g * 4 + 1];
        float il2 = 1.f / l_all[wid][g * 4 + 2];
        float il3 = 1.f / l_all[wid][g * 4 + 3];
#pragma unroll
        for (int dt = 0; dt < 4; ++dt) {
            int col = h * HSZ + dt * 16 + fr;
            o_lds[g * 4 + 0][col] = f2b_bits(oacc[dt][0] * il0);
            o_lds[g * 4 + 1][col] = f2b_bits(oacc[dt][1] * il1);
            o_lds[g * 4 + 2][col] = f2b_bits(oacc[dt][2] * il2);
            o_lds[g * 4 + 3][col] = f2b_bits(oacc[dt][3] * il3);
        }
    }
    __syncthreads();   // o_lds complete across all 12 waves

    // ---------------- proj: wave wid computes cols [wid*64, wid*64+64) -----
    const __hip_bfloat16* wb = woT + (long)(h * HSZ) * CC;
    f32x4 pacc[4] = {};
    short8 bc0 = *(const short8*)&wb[(0 * 16 + fr) * CC + g * 8];
    short8 bc1 = *(const short8*)&wb[(1 * 16 + fr) * CC + g * 8];
    short8 bc2 = *(const short8*)&wb[(2 * 16 + fr) * CC + g * 8];
    short8 bc3 = *(const short8*)&wb[(3 * 16 + fr) * CC + g * 8];
    for (int k0 = 0; k0 < CC; k0 += 32) {
        short8 bn0, bn1, bn2, bn3;
        const bool more = (k0 + 32 < CC);
        if (more) {
            bn0 = *(const short8*)&wb[(0 * 16 + fr) * CC + k0 + 32 + g * 8];
            bn1 = *(const short8*)&wb[(1 * 16 + fr) * CC + k0 + 32 + g * 8];
            bn2 = *(const short8*)&wb[(2 * 16 + fr) * CC + k0 + 32 + g * 8];
            bn3 = *(const short8*)&wb[(3 * 16 + fr) * CC + k0 + 32 + g * 8];
        }
        short8 a = *(const short8*)&o_lds[fr][k0 + g * 8];
        pacc[0] = __builtin_amdgcn_mfma_f32_16x16x32_bf16(a, bc0, pacc[0], 0, 0, 0);
        pacc[1] = __builtin_amdgcn_mfma_f32_16x16x32_bf16(a, bc1, pacc[1], 0, 0, 0);
        pacc[2] = __builtin_amdgcn_mfma_f32_16x16x32_bf16(a, bc2, pacc[2], 0, 0, 0);
        pacc[3] = __builtin_amdgcn_mfma_f32_16x16x32_bf16(a, bc3, pacc[3], 0, 0, 0);
        if (more) { bc0 = bn0; bc1 = bn1; bc2 = bn2; bc3 = bn3; }
    }

    // ---------------- residual + LN2 ----------------
    const int fq = g;
    float sreg[4][4];
    float psum[4] = {}, psq[4] = {};
#pragma unroll
    for (int n = 0; n < 4; ++n) {
        int col = h * HSZ + n * 16 + fr;
        float bv = bo[col];
#pragma unroll
        for (int j = 0; j < 4; ++j) {
            long R = (long)(b * TT + t0 + fq * 4 + j);
            float s = x[R * CC + col] + pacc[n][j] + bv;
            x[R * CC + col] = s;
            sreg[n][j] = s;
            psum[j] += s; psq[j] += s * s;
        }
    }
#pragma unroll
    for (int mk = 1; mk < 16; mk <<= 1) {
#pragma unroll
        for (int j = 0; j < 4; ++j) {
            psum[j] += __shfl_xor(psum[j], mk);
            psq[j]  += __shfl_xor(psq[j], mk);
        }
    }
    if (fr == 0) {
#pragma unroll
        for (int j = 0; j < 4; ++j) {
            sum_w[wid][fq * 4 + j] = psum[j];
            sq_w[wid][fq * 4 + j]  = psq[j];
        }
    }
    __syncthreads();
    if (tid < 16) {
        float S = 0.f, Q = 0.f;
#pragma unroll
        for (int w = 0; w < 12; ++w) { S += sum_w[w][tid]; Q += sq_w[w][tid]; }
        float mean = S * (1.0f / CC);
        float var  = Q * (1.0f / CC) - mean * mean;
        mean_s[tid] = mean;
        rs_s[tid]   = rsqrtf(var + 1e-5f);
    }
    __syncthreads();
#pragma unroll
    for (int n = 0; n < 4; ++n) {
        int col = h * HSZ + n * 16 + fr;
#pragma unroll
        for (int j = 0; j < 4; ++j) {
            int r = fq * 4 + j;
            long R = (long)(b * TT + t0 + r);
            xn[R * CC + col] = __float2bfloat16(
                (sreg[n][j] - mean_s[r]) * rs_s[r] * g2[col] + bb2[col]);
        }
    }
}

// ---------------------------------------------------------------- final LN + head
__global__ __launch_bounds__(256) void head_k(const float* __restrict__ x,
    const float* __restrict__ g, const float* __restrict__ bb,
    const float* __restrict__ Wh, const float* __restrict__ bh,
    float* __restrict__ out)
{
    int r = blockIdx.x, tid = threadIdx.x;
    const float* xr = x + (long)r * CC;
    float v[3];
    v[0] = xr[tid]; v[1] = xr[tid + 256]; v[2] = xr[tid + 512];
    float s  = v[0] + v[1] + v[2];
    float sq = v[0]*v[0] + v[1]*v[1] + v[2]*v[2];
#pragma unroll
    for (int off = 32; off > 0; off >>= 1) {
        s  += __shfl_down(s, off);
        sq += __shfl_down(sq, off);
    }
    __shared__ float ss[4], ssq[4];
    int w = tid >> 6;
    if ((tid & 63) == 0) { ss[w] = s; ssq[w] = sq; }
    __syncthreads();
    s  = ss[0] + ss[1] + ss[2] + ss[3];
    sq = ssq[0] + ssq[1] + ssq[2] + ssq[3];
    float mean = s * (1.0f / CC);
    float var  = sq * (1.0f / CC) - mean * mean;
    float rs   = rsqrtf(var + 1e-5f);

    float acc[16];
#pragma unroll
    for (int j = 0; j < 16; ++j) acc[j] = 0.f;
#pragma unroll
    for (int i = 0; i < 3; ++i) {
        int c = tid + i * 256;
        float xnv = (v[i] - mean) * rs * g[c] + bb[c];
        const float* wr = Wh + (long)c * 16;
#pragma unroll
        for (int j = 0; j < 16; ++j) acc[j] = fmaf(xnv, wr[j], acc[j]);
    }
#pragma unroll
    for (int off = 32; off > 0; off >>= 1)
#pragma unroll
        for (int j = 0; j < 16; ++j) acc[j] += __shfl_down(acc[j], off);
    __shared__ float red[4][16];
    if ((tid & 63) == 0)
#pragma unroll
        for (int j = 0; j < 16; ++j) red[w][j] = acc[j];
    __syncthreads();
    if (tid < 16)
        out[(long)r * 16 + tid] =
            red[0][tid] + red[1][tid] + red[2][tid] + red[3][tid] + bh[tid];
}

// ---------------------------------------------------------------- launch
extern "C" void kernel_launch(void* const* d_in, const int* in_sizes, int n_in,
                              void* d_out, int out_size, void* d_ws, size_t ws_size,
                              hipStream_t stream)
{
    const int*   idx  = (const int*)  d_in[0];
    const float* tok  = (const float*)d_in[1];
    const float* pos  = (const float*)d_in[2];
    const float* Wq   = (const float*)d_in[3];
    const float* Wk   = (const float*)d_in[4];
    const float* Wv   = (const float*)d_in[5];
    const float* Wo   = (const float*)d_in[6];
    const float* bo   = (const float*)d_in[7];
    const float* W1   = (const float*)d_in[8];
    const float* b1   = (const float*)d_in[9];
    const float* W2   = (const float*)d_in[10];
    const float* b2   = (const float*)d_in[11];
    const float* ln1g = (const float*)d_in[12];
    const float* ln1b = (const float*)d_in[13];
    const float* ln2g = (const float*)d_in[14];
    const float* ln2b = (const float*)d_in[15];
    const float* lnfg = (const float*)d_in[16];
    const float* lnfb = (const float*)d_in[17];
    const float* Wh   = (const float*)d_in[18];
    const float* bh   = (const float*)d_in[19];

    char* w = (char*)d_ws;
    float*          x     = (float*)w;          w += NX * 4;
    __hip_bfloat16* xn_b  = (__hip_bfloat16*)w; w += NX * 2;
    __hip_bfloat16* qkvb  = (__hip_bfloat16*)w; w += (long)BTOT * NQKV * 2;
    __hip_bfloat16* vT    = (__hip_bfloat16*)w; w += NX * 2;
    __hip_bfloat16* hb    = (__hip_bfloat16*)w; w += (long)BTOT * C4 * 2;
    __hip_bfloat16* qkvT  = (__hip_bfloat16*)w; w += (long)LL * NQKV * CC * 2;
    __hip_bfloat16* woT   = (__hip_bfloat16*)w; w += (long)LL * CC * CC * 2;
    __hip_bfloat16* w1T   = (__hip_bfloat16*)w; w += (long)LL * C4 * CC * 2;
    __hip_bfloat16* w2T   = (__hip_bfloat16*)w; w += (long)LL * CC * C4 * 2;
    float*          pbuf  = (float*)w;          w += 4 * NX * 4;

    // ---- all weight conversions upfront (4 launches) ----
    cvt_qkvT<<<dim3(12, 36, LL), 256, 0, stream>>>(Wq, Wk, Wv, qkvT);
    cvtT_k<<<dim3(12, 12, LL), 256, 0, stream>>>(Wo, woT, CC, CC,
        (long)CC * CC, (long)CC * CC);
    cvtT_k<<<dim3(48, 12, LL), 256, 0, stream>>>(W1, w1T, CC, C4,
        (long)CC * C4, (long)CC * C4);
    cvtT_k<<<dim3(12, 48, LL), 256, 0, stream>>>(W2, w2T, C4, CC,
        (long)C4 * CC, (long)C4 * CC);

    embed_k<<<BTOT, 256, 0, stream>>>(idx, tok, pos, x);
    ln_b<<<BTOT, 256, 0, stream>>>(x, ln1g, ln1b, xn_b);   // layer-0 LN1

    for (int l = 0; l < LL; ++l) {
        // QKV: M=2048, N=2304, K=768; 576 blocks
        gemm_bf16<1><<<dim3(NQKV / 128, BTOT / 64), 256, 0, stream>>>(
            xn_b, qkvT + (long)l * NQKV * CC, qkvb, nullptr, nullptr, vT,
            CC, CC, CC, NQKV);

        // fused attention + proj + residual + LN2 (writes x, xn)
        attn_proj<<<dim3(TT / 16, 4), 768, 0, stream>>>(
            qkvb, vT, woT + (long)l * CC * CC, bo + l * CC,
            ln2g + l * CC, ln2b + l * CC, x, xn_b);

        // MLP1: M=2048, N=3072, K=768; 768 blocks
        gemm_bf16<2><<<dim3(C4 / 128, BTOT / 64), 256, 0, stream>>>(
            xn_b, w1T + (long)l * C4 * CC, hb, nullptr, b1 + l * C4, nullptr,
            CC, CC, CC, C4);

        // MLP2: M=2048, N=768, K=3072 split 4x768 -> fp32 partials; 768 blocks
        gemm_bf16<5><<<dim3(CC / 128, BTOT / 64, 4), 256, 0, stream>>>(
            hb, w2T + (long)l * CC * C4, nullptr, pbuf, nullptr, nullptr,
            768, C4, C4, CC);

        // x += sum(partials) + b2; xn = LN1(next layer) (skip LN on last)
        if (l < LL - 1) {
            red_ln<true><<<BTOT, 256, 0, stream>>>(x, pbuf, b2 + l * CC,
                ln1g + (l + 1) * CC, ln1b + (l + 1) * CC, xn_b);
        } else {
            red_ln<false><<<BTOT, 256, 0, stream>>>(x, pbuf, b2 + l * CC,
                nullptr, nullptr, nullptr);
        }
    }

    head_k<<<BTOT, 256, 0, stream>>>(x, lnfg, lnfb, Wh, bh, (float*)d_out);
}

// Round 11
// 1504.283 us; speedup vs baseline: 1.3239x; 1.3239x over previous
//
#include <hip/hip_runtime.h>
#include <hip/hip_bf16.h>
#include <math.h>

#define TT   512
#define CC   768
#define HH   12
#define HSZ  64
#define LL   12
#define C4   3072
#define BTOT 2048   // B*T
#define NQKV 2304   // 3*C
#define NX   ((long)BTOT * CC)

typedef __attribute__((ext_vector_type(8))) short short8;
typedef __attribute__((ext_vector_type(4))) float f32x4;

__device__ __forceinline__ unsigned short f2b_bits(float f) {
    unsigned u = __float_as_uint(f);
    return (unsigned short)((u + 0x7fffu + ((u >> 16) & 1u)) >> 16);
}

// async global->LDS, 16B per lane; LDS dest is wave-uniform base + lane*16B
__device__ __forceinline__ void gl_lds16(const void* g, void* l) {
    __builtin_amdgcn_global_load_lds(
        (const __attribute__((address_space(1))) unsigned int*)g,
        (__attribute__((address_space(3))) unsigned int*)l,
        16, 0, 0);
}

// ---------------------------------------------------------------- embedding
__global__ __launch_bounds__(256) void embed_k(const int* __restrict__ idx,
    const float* __restrict__ tok, const float* __restrict__ pos,
    float* __restrict__ x)
{
    int r   = blockIdx.x;
    int tid = threadIdx.x;
    int t   = r & (TT - 1);
    long id = idx[r];
    const float* te = tok + id * (long)CC;
    const float* pe = pos + (long)t * CC;
    float* xr = x + (long)r * CC;
#pragma unroll
    for (int i = 0; i < 3; ++i) {
        int c = tid + i * 256;
        xr[c] = te[c] + pe[c];
    }
}

// ---------------------------------------------------------------- layernorm (fp32 in, bf16 out)
__global__ __launch_bounds__(256) void ln_b(const float* __restrict__ x,
    const float* __restrict__ g, const float* __restrict__ b,
    __hip_bfloat16* __restrict__ y)
{
    int r = blockIdx.x, tid = threadIdx.x;
    const float* xr = x + (long)r * CC;
    float v[3];
    v[0] = xr[tid]; v[1] = xr[tid + 256]; v[2] = xr[tid + 512];
    float s  = v[0] + v[1] + v[2];
    float sq = v[0]*v[0] + v[1]*v[1] + v[2]*v[2];
#pragma unroll
    for (int off = 32; off > 0; off >>= 1) {
        s  += __shfl_down(s, off);
        sq += __shfl_down(sq, off);
    }
    __shared__ float ss[4], ssq[4];
    int w = tid >> 6;
    if ((tid & 63) == 0) { ss[w] = s; ssq[w] = sq; }
    __syncthreads();
    s  = ss[0] + ss[1] + ss[2] + ss[3];
    sq = ssq[0] + ssq[1] + ssq[2] + ssq[3];
    float mean = s * (1.0f / CC);
    float var  = sq * (1.0f / CC) - mean * mean;
    float rs   = rsqrtf(var + 1e-5f);
    __hip_bfloat16* yr = y + (long)r * CC;
#pragma unroll
    for (int i = 0; i < 3; ++i) {
        int c = tid + i * 256;
        yr[c] = __float2bfloat16((v[i] - mean) * rs * g[c] + b[c]);
    }
}

// ---------------------------------------- fused split-K reduce + residual + LN
// x[r] += p0[r]+p1[r]+p2[r]+p3[r] + bias; optionally y = LN(x; g,b) in bf16.
template <bool DOLN>
__global__ __launch_bounds__(256) void red_ln(float* __restrict__ x,
    const float* __restrict__ p, const float* __restrict__ bias,
    const float* __restrict__ g, const float* __restrict__ b,
    __hip_bfloat16* __restrict__ y)
{
    int r = blockIdx.x, tid = threadIdx.x;
    float* xr = x + (long)r * CC;
    const float* pr = p + (long)r * CC;
    float v[3];
#pragma unroll
    for (int i = 0; i < 3; ++i) {
        int c = tid + i * 256;
        float s = xr[c] + bias[c];
        s += pr[c];
        s += pr[c + 1 * NX];
        s += pr[c + 2 * NX];
        s += pr[c + 3 * NX];
        xr[c] = s;
        v[i] = s;
    }
    if (!DOLN) return;
    float s  = v[0] + v[1] + v[2];
    float sq = v[0]*v[0] + v[1]*v[1] + v[2]*v[2];
#pragma unroll
    for (int off = 32; off > 0; off >>= 1) {
        s  += __shfl_down(s, off);
        sq += __shfl_down(sq, off);
    }
    __shared__ float ss[4], ssq[4];
    int w = tid >> 6;
    if ((tid & 63) == 0) { ss[w] = s; ssq[w] = sq; }
    __syncthreads();
    s  = ss[0] + ss[1] + ss[2] + ss[3];
    sq = ssq[0] + ssq[1] + ssq[2] + ssq[3];
    float mean = s * (1.0f / CC);
    float var  = sq * (1.0f / CC) - mean * mean;
    float rs   = rsqrtf(var + 1e-5f);
    __hip_bfloat16* yr = y + (long)r * CC;
#pragma unroll
    for (int i = 0; i < 3; ++i) {
        int c = tid + i * 256;
        yr[c] = __float2bfloat16((v[i] - mean) * rs * g[c] + b[c]);
    }
}

// ------------------------------------------------- weight convert/transpose
// src fp32 [R][D] -> dst bf16 [D][R]; 64x64 tiles; grid (D/64, R/64, L)
__global__ __launch_bounds__(256) void cvtT_k(const float* __restrict__ src,
    __hip_bfloat16* __restrict__ dst, int R, int D, long sSrc, long sDst)
{
    src += (long)blockIdx.z * sSrc;
    dst += (long)blockIdx.z * sDst;
    __shared__ float t[64][65];
    int d0 = blockIdx.x * 64, r0 = blockIdx.y * 64;
    int tid = threadIdx.x;
#pragma unroll
    for (int i = 0; i < 4; ++i) {
        int flat = tid + i * 256;
        int r = flat >> 4, c4 = (flat & 15) * 4;
        float4 v = *(const float4*)&src[(long)(r0 + r) * D + d0 + c4];
        t[r][c4 + 0] = v.x; t[r][c4 + 1] = v.y;
        t[r][c4 + 2] = v.z; t[r][c4 + 3] = v.w;
    }
    __syncthreads();
#pragma unroll
    for (int i = 0; i < 4; ++i) {
        int flat = tid + i * 256;
        int n = flat >> 4, kq = (flat & 15) * 4;
        ushort4 o;
        o.x = f2b_bits(t[kq + 0][n]); o.y = f2b_bits(t[kq + 1][n]);
        o.z = f2b_bits(t[kq + 2][n]); o.w = f2b_bits(t[kq + 3][n]);
        *(ushort4*)&dst[(long)(d0 + n) * R + r0 + kq] = o;
    }
}

// Wq/Wk/Wv [L][h][768][64] -> qkvT_all [L][2304][768]; grid (12, 36, L)
__global__ __launch_bounds__(256) void cvt_qkvT(const float* __restrict__ Wq,
    const float* __restrict__ Wk, const float* __restrict__ Wv,
    __hip_bfloat16* __restrict__ out)
{
    int c0 = blockIdx.x * 64;
    int g  = blockIdx.y;
    int l  = blockIdx.z;
    int which = g / 12, h = g % 12;
    const long wAtt = (long)HH * CC * HSZ;
    const float* src = (which == 0 ? Wq : which == 1 ? Wk : Wv)
                       + l * wAtt + (long)h * CC * HSZ;   // [768][64]
    __hip_bfloat16* dst = out + (long)l * NQKV * CC + (long)(which * CC + h * HSZ) * CC;
    __shared__ float t[64][65];
    int tid = threadIdx.x;
#pragma unroll
    for (int i = 0; i < 4; ++i) {
        int flat = tid + i * 256;
        int r = flat >> 4, c4 = (flat & 15) * 4;
        float4 v = *(const float4*)&src[(long)(c0 + r) * HSZ + c4];
        t[r][c4 + 0] = v.x; t[r][c4 + 1] = v.y;
        t[r][c4 + 2] = v.z; t[r][c4 + 3] = v.w;
    }
    __syncthreads();
#pragma unroll
    for (int i = 0; i < 4; ++i) {
        int flat = tid + i * 256;
        int n = flat >> 4, kq = (flat & 15) * 4;
        ushort4 o;
        o.x = f2b_bits(t[kq + 0][n]); o.y = f2b_bits(t[kq + 1][n]);
        o.z = f2b_bits(t[kq + 2][n]); o.w = f2b_bits(t[kq + 3][n]);
        *(ushort4*)&dst[(long)n * CC + c0 + kq] = o;
    }
}

// ---------------------------------------------------------------- bf16 MFMA GEMM
// C[M,N] = A[M,K] @ B[K,N]; A bf16 [M][lda], BT bf16 [N][ldb] (=B^T); K%32==0,
// K/32 >= 3. Tile 64 x 128, BK=32, 4 waves (2x2), each wave 32x64 out.
// Depth-4 pipeline: 4 LDS buffers, 3 tiles in flight via global_load_lds,
// counted s_waitcnt vmcnt(N) + raw s_barrier (never drains to 0 mid-loop).
// T1: bijective XCD swizzle of (bx,by) within each z-slice (slice % 8 == 0)
// so each XCD's L2 holds one contiguous tile range (A-slab / B-panel reuse).
// EPI 1: QKV (cols<1536 -> Cb, cols>=1536 -> Vt transposed);
// EPI 2: +bias exact-GELU -> bf16;
// EPI 5: split-K over blockIdx.z: store fp32 partial to Cf + sk*NX (no bias).
template <int EPI>
__global__ __launch_bounds__(256, 3) void gemm_bf16(
    const __hip_bfloat16* __restrict__ A,
    const __hip_bfloat16* __restrict__ BT,
    __hip_bfloat16* __restrict__ Cb, float* __restrict__ Cf,
    const float* __restrict__ bias, __hip_bfloat16* __restrict__ Vt,
    int K, int lda, int ldb, int ldc)
{
    __shared__ short Asm[4][64 * 32];
    __shared__ short Bsm[4][128 * 32];
    const int tid  = threadIdx.x;
    const int lane = tid & 63;
    const int wid  = tid >> 6;
    const int wm = wid >> 1, wn = wid & 1;

    // T1 XCD swizzle: hardware block (x,y) computes logical tile swz
    const int gx = gridDim.x;
    const int slice = gx * gridDim.y;            // divisible by 8
    int flat = blockIdx.y * gx + blockIdx.x;
    int swz  = (flat & 7) * (slice >> 3) + (flat >> 3);
    const int row0 = (swz / gx) * 64, col0 = (swz % gx) * 128;
    const int sk = (EPI == 5) ? blockIdx.z : 0;

    const int gr = tid >> 2;               // staging row 0..63
    // swizzled source column-block: cb = (pos + (row>>1)) & 3
    const int cb = ((tid & 3) + (tid >> 3)) & 3;
    const int gk = cb * 8;                 // k offset in shorts
    const __hip_bfloat16* Ap = A  + (long)(row0 + gr) * lda + sk * K + gk;
    const __hip_bfloat16* Bp = BT + (long)(col0 + gr) * ldb + sk * K + gk;
    const int lofs = wid * 512;            // per-wave LDS segment (shorts)

    f32x4 acc[2][4] = {};
    const int fr = lane & 15, g = lane >> 4;

    // swizzled read offsets (shorts), fixed per lane: row*32 + ((g-(row>>1))&3)*8
    int offA[2], offB[4];
#pragma unroll
    for (int m = 0; m < 2; ++m) {
        int row = wm * 32 + m * 16 + fr;
        offA[m] = row * 32 + (((g - (row >> 1)) & 3) * 8);
    }
#pragma unroll
    for (int n = 0; n < 4; ++n) {
        int row = wn * 64 + n * 16 + fr;
        offB[n] = row * 32 + (((g - (row >> 1)) & 3) * 8);
    }

#define STAGE(buf)                                                          \
    do {                                                                    \
        gl_lds16(Ap, &Asm[buf][lofs]);                                      \
        gl_lds16(Bp, &Bsm[buf][lofs]);                                      \
        gl_lds16(Bp + (long)64 * ldb, &Bsm[buf][lofs + 64 * 32]);           \
        Ap += 32; Bp += 32;                                                 \
    } while (0)

    // prologue: tiles 0,1,2 in flight (3 loads each)
    STAGE(0); STAGE(1); STAGE(2);

    const int nt = K >> 5;                 // >= 3
    for (int t = 0; t < nt; ++t) {
        if (t < nt - 2)       asm volatile("s_waitcnt vmcnt(6)" ::: "memory");
        else if (t == nt - 2) asm volatile("s_waitcnt vmcnt(3)" ::: "memory");
        else                  asm volatile("s_waitcnt vmcnt(0)" ::: "memory");
        __builtin_amdgcn_s_barrier();      // all waves' tile-t loads resident;
        __builtin_amdgcn_sched_barrier(0); // also fences reuse of buf[(t+3)&3]
        if (t + 3 < nt) STAGE((t + 3) & 3);

        const int cur = t & 3;
        short8 af[2], bf[4];
#pragma unroll
        for (int m = 0; m < 2; ++m)
            af[m] = *(const short8*)&Asm[cur][offA[m]];
#pragma unroll
        for (int n = 0; n < 4; ++n)
            bf[n] = *(const short8*)&Bsm[cur][offB[n]];
#pragma unroll
        for (int m = 0; m < 2; ++m)
#pragma unroll
            for (int n = 0; n < 4; ++n)
                acc[m][n] = __builtin_amdgcn_mfma_f32_16x16x32_bf16(
                    af[m], bf[n], acc[m][n], 0, 0, 0);
    }
#undef STAGE

    const int fq = lane >> 4;
    float* pout = (EPI == 5) ? (Cf + (long)sk * NX) : nullptr;
#pragma unroll
    for (int m = 0; m < 2; ++m) {
        int rbase = row0 + wm * 32 + m * 16 + fq * 4;
#pragma unroll
        for (int n = 0; n < 4; ++n) {
            int col = col0 + wn * 64 + n * 16 + fr;
            if (EPI == 1 && col >= 1536) {
                int hd = col - 1536;
                int b = rbase >> 9, t = rbase & (TT - 1);
                ushort4 o;
                o.x = f2b_bits(acc[m][n][0]); o.y = f2b_bits(acc[m][n][1]);
                o.z = f2b_bits(acc[m][n][2]); o.w = f2b_bits(acc[m][n][3]);
                *(ushort4*)&Vt[((long)(b * HH + (hd >> 6)) * HSZ + (hd & 63)) * TT + t] = o;
                continue;
            }
            float bv = (EPI == 2) ? bias[col] : 0.f;
#pragma unroll
            for (int j = 0; j < 4; ++j) {
                long row = rbase + j;
                float v = acc[m][n][j];
                if (EPI == 1) {
                    Cb[row * ldc + col] = __float2bfloat16(v);
                } else if (EPI == 2) {
                    v += bv;
                    v = 0.5f * v * (1.0f + erff(v * 0.70710678118654752f));
                    Cb[row * ldc + col] = __float2bfloat16(v);
                } else { // EPI == 5
                    pout[row * ldc + col] = v;
                }
            }
        }
    }
}

// ---------------------------------------------------------------- MFMA flash attention
// qkv [2048][2304] bf16 (q|k cols used), vT [B][H][64][512] bf16.
// One wave per (b,h,16-query tile). S^T = mfma(K, Q) -> q index lane-local.
// K register-double-buffered (prefetch next chunk), V prefetched pre-softmax.
// T1: bijective XCD swizzle so each XCD keeps whole (b,h) K/V streams in L2.
__global__ __launch_bounds__(64) void attn_mfma(
    const __hip_bfloat16* __restrict__ qkv,
    const __hip_bfloat16* __restrict__ vT,
    __hip_bfloat16* __restrict__ o)
{
    int flat = blockIdx.x + 32 * (blockIdx.y + 12 * blockIdx.z);
    int swz  = (flat & 7) * 192 + (flat >> 3);     // 1536 blocks, 8 XCDs
    const int qt = swz & 31;
    const int h  = (swz >> 5) % 12;
    const int b  = swz / 384;
    const int lane = threadIdx.x;
    const int t0 = qt * 16;
    const int fr = lane & 15, g = lane >> 4;

    __shared__ unsigned short P_lds[16 * 40];
    __shared__ float corr_lds[16], l_lds[16];

    const long qbase = ((long)(b * TT + t0 + fr)) * NQKV + h * HSZ + g * 8;
    short8 qf0 = *(const short8*)(qkv + qbase);
    short8 qf1 = *(const short8*)(qkv + qbase + 32);

    f32x4 oacc[4] = {};
    float m_run = -3.0e38f, l_run = 0.f;
    const int t_lane = t0 + fr;
    const int smax = t0 + 15;
    const long kcol = CC + h * HSZ + g * 8;
    const long vrow = (((long)(b * HH + h) * HSZ) + fr) * TT + g * 8;

    // preload K chunk 0 (rows fr, 16+fr)
    short8 ka0, ka1, ka2, ka3;
    {
        long kb0 = ((long)(b * TT + fr)) * NQKV + kcol;
        long kb1 = ((long)(b * TT + 16 + fr)) * NQKV + kcol;
        ka0 = *(const short8*)(qkv + kb0);
        ka1 = *(const short8*)(qkv + kb0 + 32);
        ka2 = *(const short8*)(qkv + kb1);
        ka3 = *(const short8*)(qkv + kb1 + 32);
    }

    for (int s0 = 0; s0 <= smax; s0 += 32) {
        // S^T for two 16-key subtiles from registers
        f32x4 st0 = {}, st1 = {};
        st0 = __builtin_amdgcn_mfma_f32_16x16x32_bf16(ka0, qf0, st0, 0, 0, 0);
        st0 = __builtin_amdgcn_mfma_f32_16x16x32_bf16(ka1, qf1, st0, 0, 0, 0);
        st1 = __builtin_amdgcn_mfma_f32_16x16x32_bf16(ka2, qf0, st1, 0, 0, 0);
        st1 = __builtin_amdgcn_mfma_f32_16x16x32_bf16(ka3, qf1, st1, 0, 0, 0);

        // prefetch next K chunk (regs) — lands during softmax
        const bool more = (s0 + 32 <= smax);
        short8 kn0, kn1, kn2, kn3;
        if (more) {
            long kb0 = ((long)(b * TT + s0 + 32 + fr)) * NQKV + kcol;
            long kb1 = ((long)(b * TT + s0 + 48 + fr)) * NQKV + kcol;
            kn0 = *(const short8*)(qkv + kb0);
            kn1 = *(const short8*)(qkv + kb0 + 32);
            kn2 = *(const short8*)(qkv + kb1);
            kn3 = *(const short8*)(qkv + kb1 + 32);
        }
        // prefetch V chunk (regs) — lands during softmax/pack
        short8 vc0 = *(const short8*)(vT + vrow + s0);
        short8 vc1 = *(const short8*)(vT + vrow + 16 * TT + s0);
        short8 vc2 = *(const short8*)(vT + vrow + 32 * TT + s0);
        short8 vc3 = *(const short8*)(vT + vrow + 48 * TT + s0);

        // scale + causal mask + online softmax stats (q = fr, lane-local)
        float p[8];
        float mx = -3.0e38f;
#pragma unroll
        for (int j = 0; j < 4; ++j) {
            int s = s0 + g * 4 + j;
            float v = st0[j] * 0.125f;
            v = (s <= t_lane) ? v : -3.0e38f;
            p[j] = v; mx = fmaxf(mx, v);
        }
#pragma unroll
        for (int j = 0; j < 4; ++j) {
            int s = s0 + 16 + g * 4 + j;
            float v = st1[j] * 0.125f;
            v = (s <= t_lane) ? v : -3.0e38f;
            p[4 + j] = v; mx = fmaxf(mx, v);
        }
        mx = fmaxf(mx, __shfl_xor(mx, 16));
        mx = fmaxf(mx, __shfl_xor(mx, 32));
        float mnew = fmaxf(m_run, mx);
        float corr = __expf(m_run - mnew);
        float psum = 0.f;
#pragma unroll
        for (int i = 0; i < 8; ++i) {
            float e = __expf(p[i] - mnew);
            p[i] = e; psum += e;
        }
        psum += __shfl_xor(psum, 16);
        psum += __shfl_xor(psum, 32);
        l_run = l_run * corr + psum;
        m_run = mnew;

        __syncthreads();
        if (lane < 16) corr_lds[lane] = corr;
        unsigned u0 = (unsigned)f2b_bits(p[0]) | ((unsigned)f2b_bits(p[1]) << 16);
        unsigned u1 = (unsigned)f2b_bits(p[2]) | ((unsigned)f2b_bits(p[3]) << 16);
        unsigned u2 = (unsigned)f2b_bits(p[4]) | ((unsigned)f2b_bits(p[5]) << 16);
        unsigned u3 = (unsigned)f2b_bits(p[6]) | ((unsigned)f2b_bits(p[7]) << 16);
        *(unsigned*)&P_lds[fr * 40 + g * 4]          = u0;
        *(unsigned*)&P_lds[fr * 40 + g * 4 + 2]      = u1;
        *(unsigned*)&P_lds[fr * 40 + 16 + g * 4]     = u2;
        *(unsigned*)&P_lds[fr * 40 + 16 + g * 4 + 2] = u3;
        __syncthreads();

        float cr0 = corr_lds[g * 4 + 0], cr1 = corr_lds[g * 4 + 1];
        float cr2 = corr_lds[g * 4 + 2], cr3 = corr_lds[g * 4 + 3];
        short8 pf = *(const short8*)&P_lds[fr * 40 + g * 8];
        oacc[0][0] *= cr0; oacc[0][1] *= cr1; oacc[0][2] *= cr2; oacc[0][3] *= cr3;
        oacc[0] = __builtin_amdgcn_mfma_f32_16x16x32_bf16(pf, vc0, oacc[0], 0, 0, 0);
        oacc[1][0] *= cr0; oacc[1][1] *= cr1; oacc[1][2] *= cr2; oacc[1][3] *= cr3;
        oacc[1] = __builtin_amdgcn_mfma_f32_16x16x32_bf16(pf, vc1, oacc[1], 0, 0, 0);
        oacc[2][0] *= cr0; oacc[2][1] *= cr1; oacc[2][2] *= cr2; oacc[2][3] *= cr3;
        oacc[2] = __builtin_amdgcn_mfma_f32_16x16x32_bf16(pf, vc2, oacc[2], 0, 0, 0);
        oacc[3][0] *= cr0; oacc[3][1] *= cr1; oacc[3][2] *= cr2; oacc[3][3] *= cr3;
        oacc[3] = __builtin_amdgcn_mfma_f32_16x16x32_bf16(pf, vc3, oacc[3], 0, 0, 0);

        if (more) { ka0 = kn0; ka1 = kn1; ka2 = kn2; ka3 = kn3; }
    }

    __syncthreads();
    if (lane < 16) l_lds[lane] = l_run;
    __syncthreads();
    float il0 = 1.f / l_lds[g * 4 + 0], il1 = 1.f / l_lds[g * 4 + 1];
    float il2 = 1.f / l_lds[g * 4 + 2], il3 = 1.f / l_lds[g * 4 + 3];
#pragma unroll
    for (int dt = 0; dt < 4; ++dt) {
        long cbase = (long)(b * TT + t0) * CC + h * HSZ + dt * 16 + fr;
        o[cbase + (g * 4 + 0) * (long)CC] = __float2bfloat16(oacc[dt][0] * il0);
        o[cbase + (g * 4 + 1) * (long)CC] = __float2bfloat16(oacc[dt][1] * il1);
        o[cbase + (g * 4 + 2) * (long)CC] = __float2bfloat16(oacc[dt][2] * il2);
        o[cbase + (g * 4 + 3) * (long)CC] = __float2bfloat16(oacc[dt][3] * il3);
    }
}

// ---------------------------------------------------------------- final LN + head
__global__ __launch_bounds__(256) void head_k(const float* __restrict__ x,
    const float* __restrict__ g, const float* __restrict__ bb,
    const float* __restrict__ Wh, const float* __restrict__ bh,
    float* __restrict__ out)
{
    int r = blockIdx.x, tid = threadIdx.x;
    const float* xr = x + (long)r * CC;
    float v[3];
    v[0] = xr[tid]; v[1] = xr[tid + 256]; v[2] = xr[tid + 512];
    float s  = v[0] + v[1] + v[2];
    float sq = v[0]*v[0] + v[1]*v[1] + v[2]*v[2];
#pragma unroll
    for (int off = 32; off > 0; off >>= 1) {
        s  += __shfl_down(s, off);
        sq += __shfl_down(sq, off);
    }
    __shared__ float ss[4], ssq[4];
    int w = tid >> 6;
    if ((tid & 63) == 0) { ss[w] = s; ssq[w] = sq; }
    __syncthreads();
    s  = ss[0] + ss[1] + ss[2] + ss[3];
    sq = ssq[0] + ssq[1] + ssq[2] + ssq[3];
    float mean = s * (1.0f / CC);
    float var  = sq * (1.0f / CC) - mean * mean;
    float rs   = rsqrtf(var + 1e-5f);

    float acc[16];
#pragma unroll
    for (int j = 0; j < 16; ++j) acc[j] = 0.f;
#pragma unroll
    for (int i = 0; i < 3; ++i) {
        int c = tid + i * 256;
        float xnv = (v[i] - mean) * rs * g[c] + bb[c];
        const float* wr = Wh + (long)c * 16;
#pragma unroll
        for (int j = 0; j < 16; ++j) acc[j] = fmaf(xnv, wr[j], acc[j]);
    }
#pragma unroll
    for (int off = 32; off > 0; off >>= 1)
#pragma unroll
        for (int j = 0; j < 16; ++j) acc[j] += __shfl_down(acc[j], off);
    __shared__ float red[4][16];
    if ((tid & 63) == 0)
#pragma unroll
        for (int j = 0; j < 16; ++j) red[w][j] = acc[j];
    __syncthreads();
    if (tid < 16)
        out[(long)r * 16 + tid] =
            red[0][tid] + red[1][tid] + red[2][tid] + red[3][tid] + bh[tid];
}

// ---------------------------------------------------------------- launch
extern "C" void kernel_launch(void* const* d_in, const int* in_sizes, int n_in,
                              void* d_out, int out_size, void* d_ws, size_t ws_size,
                              hipStream_t stream)
{
    const int*   idx  = (const int*)  d_in[0];
    const float* tok  = (const float*)d_in[1];
    const float* pos  = (const float*)d_in[2];
    const float* Wq   = (const float*)d_in[3];
    const float* Wk   = (const float*)d_in[4];
    const float* Wv   = (const float*)d_in[5];
    const float* Wo   = (const float*)d_in[6];
    const float* bo   = (const float*)d_in[7];
    const float* W1   = (const float*)d_in[8];
    const float* b1   = (const float*)d_in[9];
    const float* W2   = (const float*)d_in[10];
    const float* b2   = (const float*)d_in[11];
    const float* ln1g = (const float*)d_in[12];
    const float* ln1b = (const float*)d_in[13];
    const float* ln2g = (const float*)d_in[14];
    const float* ln2b = (const float*)d_in[15];
    const float* lnfg = (const float*)d_in[16];
    const float* lnfb = (const float*)d_in[17];
    const float* Wh   = (const float*)d_in[18];
    const float* bh   = (const float*)d_in[19];

    char* w = (char*)d_ws;
    float*          x     = (float*)w;          w += NX * 4;
    __hip_bfloat16* xn_b  = (__hip_bfloat16*)w; w += NX * 2;
    __hip_bfloat16* qkvb  = (__hip_bfloat16*)w; w += (long)BTOT * NQKV * 2;
    __hip_bfloat16* vT    = (__hip_bfloat16*)w; w += NX * 2;
    __hip_bfloat16* o_b   = (__hip_bfloat16*)w; w += NX * 2;
    __hip_bfloat16* hb    = (__hip_bfloat16*)w; w += (long)BTOT * C4 * 2;
    __hip_bfloat16* qkvT  = (__hip_bfloat16*)w; w += (long)LL * NQKV * CC * 2;
    __hip_bfloat16* woT   = (__hip_bfloat16*)w; w += (long)LL * CC * CC * 2;
    __hip_bfloat16* w1T   = (__hip_bfloat16*)w; w += (long)LL * C4 * CC * 2;
    __hip_bfloat16* w2T   = (__hip_bfloat16*)w; w += (long)LL * CC * C4 * 2;
    float*          pbuf  = (float*)w;          w += 4 * NX * 4;

    // ---- all weight conversions upfront (4 launches) ----
    cvt_qkvT<<<dim3(12, 36, LL), 256, 0, stream>>>(Wq, Wk, Wv, qkvT);
    cvtT_k<<<dim3(12, 12, LL), 256, 0, stream>>>(Wo, woT, CC, CC,
        (long)CC * CC, (long)CC * CC);
    cvtT_k<<<dim3(48, 12, LL), 256, 0, stream>>>(W1, w1T, CC, C4,
        (long)CC * C4, (long)CC * C4);
    cvtT_k<<<dim3(12, 48, LL), 256, 0, stream>>>(W2, w2T, C4, CC,
        (long)C4 * CC, (long)C4 * CC);

    embed_k<<<BTOT, 256, 0, stream>>>(idx, tok, pos, x);
    ln_b<<<BTOT, 256, 0, stream>>>(x, ln1g, ln1b, xn_b);   // layer-0 LN1

    for (int l = 0; l < LL; ++l) {
        // QKV: M=2048, N=2304, K=768; 576 blocks
        gemm_bf16<1><<<dim3(NQKV / 128, BTOT / 64), 256, 0, stream>>>(
            xn_b, qkvT + (long)l * NQKV * CC, qkvb, nullptr, nullptr, vT,
            CC, CC, CC, NQKV);

        attn_mfma<<<dim3(TT / 16, HH, 4), 64, 0, stream>>>(qkvb, vT, o_b);

        // proj: M=2048, N=768, K=768 split 4x192 -> fp32 partials; 768 blocks
        gemm_bf16<5><<<dim3(CC / 128, BTOT / 64, 4), 256, 0, stream>>>(
            o_b, woT + (long)l * CC * CC, nullptr, pbuf, nullptr, nullptr,
            192, CC, CC, CC);

        // x += sum(partials) + bo; xn = LN2(x)
        red_ln<true><<<BTOT, 256, 0, stream>>>(x, pbuf, bo + l * CC,
            ln2g + l * CC, ln2b + l * CC, xn_b);

        // MLP1: M=2048, N=3072, K=768; 768 blocks
        gemm_bf16<2><<<dim3(C4 / 128, BTOT / 64), 256, 0, stream>>>(
            xn_b, w1T + (long)l * C4 * CC, hb, nullptr, b1 + l * C4, nullptr,
            CC, CC, CC, C4);

        // MLP2: M=2048, N=768, K=3072 split 4x768 -> fp32 partials; 768 blocks
        gemm_bf16<5><<<dim3(CC / 128, BTOT / 64, 4), 256, 0, stream>>>(
            hb, w2T + (long)l * CC * C4, nullptr, pbuf, nullptr, nullptr,
            768, C4, C4, CC);

        // x += sum(partials) + b2; xn = LN1(next layer) (skip LN on last)
        if (l < LL - 1) {
            red_ln<true><<<BTOT, 256, 0, stream>>>(x, pbuf, b2 + l * CC,
                ln1g + (l + 1) * CC, ln1b + (l + 1) * CC, xn_b);
        } else {
            red_ln<false><<<BTOT, 256, 0, stream>>>(x, pbuf, b2 + l * CC,
                nullptr, nullptr, nullptr);
        }
    }

    head_k<<<BTOT, 256, 0, stream>>>(x, lnfg, lnfb, Wh, bh, (float*)d_out);
}

// Round 12
// 1446.867 us; speedup vs baseline: 1.3764x; 1.0397x over previous
//
#include <hip/hip_runtime.h>
#include <hip/hip_bf16.h>
#include <math.h>

#define TT   512
#define CC   768
#define HH   12
#define HSZ  64
#define LL   12
#define C4   3072
#define BTOT 2048   // B*T
#define NQKV 2304   // 3*C
#define NX   ((long)BTOT * CC)

typedef __attribute__((ext_vector_type(8))) short short8;
typedef __attribute__((ext_vector_type(4))) float f32x4;

__device__ __forceinline__ unsigned short f2b_bits(float f) {
    unsigned u = __float_as_uint(f);
    return (unsigned short)((u + 0x7fffu + ((u >> 16) & 1u)) >> 16);
}
__device__ __forceinline__ float b2f(unsigned short b) {
    return __uint_as_float((unsigned)b << 16);
}

// async global->LDS, 16B per lane; LDS dest is wave-uniform base + lane*16B
__device__ __forceinline__ void gl_lds16(const void* g, void* l) {
    __builtin_amdgcn_global_load_lds(
        (const __attribute__((address_space(1))) unsigned int*)g,
        (__attribute__((address_space(3))) unsigned int*)l,
        16, 0, 0);
}

// ---------------------------------------------------------------- embedding
__global__ __launch_bounds__(256) void embed_k(const int* __restrict__ idx,
    const float* __restrict__ tok, const float* __restrict__ pos,
    float* __restrict__ x)
{
    int r   = blockIdx.x;
    int tid = threadIdx.x;
    int t   = r & (TT - 1);
    long id = idx[r];
    const float* te = tok + id * (long)CC;
    const float* pe = pos + (long)t * CC;
    float* xr = x + (long)r * CC;
#pragma unroll
    for (int i = 0; i < 3; ++i) {
        int c = tid + i * 256;
        xr[c] = te[c] + pe[c];
    }
}

// ---------------------------------------------------------------- layernorm (fp32 in, bf16 out)
__global__ __launch_bounds__(256) void ln_b(const float* __restrict__ x,
    const float* __restrict__ g, const float* __restrict__ b,
    __hip_bfloat16* __restrict__ y)
{
    int r = blockIdx.x, tid = threadIdx.x;
    const float* xr = x + (long)r * CC;
    float v[3];
    v[0] = xr[tid]; v[1] = xr[tid + 256]; v[2] = xr[tid + 512];
    float s  = v[0] + v[1] + v[2];
    float sq = v[0]*v[0] + v[1]*v[1] + v[2]*v[2];
#pragma unroll
    for (int off = 32; off > 0; off >>= 1) {
        s  += __shfl_down(s, off);
        sq += __shfl_down(sq, off);
    }
    __shared__ float ss[4], ssq[4];
    int w = tid >> 6;
    if ((tid & 63) == 0) { ss[w] = s; ssq[w] = sq; }
    __syncthreads();
    s  = ss[0] + ss[1] + ss[2] + ss[3];
    sq = ssq[0] + ssq[1] + ssq[2] + ssq[3];
    float mean = s * (1.0f / CC);
    float var  = sq * (1.0f / CC) - mean * mean;
    float rs   = rsqrtf(var + 1e-5f);
    __hip_bfloat16* yr = y + (long)r * CC;
#pragma unroll
    for (int i = 0; i < 3; ++i) {
        int c = tid + i * 256;
        yr[c] = __float2bfloat16((v[i] - mean) * rs * g[c] + b[c]);
    }
}

// ---------------------------------------- fused split-K reduce + residual + LN
// x[r] += sum of 4 bf16 partial slices + bias; optionally y = LN(x) bf16.
template <bool DOLN>
__global__ __launch_bounds__(256) void red_ln(float* __restrict__ x,
    const unsigned short* __restrict__ p, const float* __restrict__ bias,
    const float* __restrict__ g, const float* __restrict__ b,
    __hip_bfloat16* __restrict__ y)
{
    int r = blockIdx.x, tid = threadIdx.x;
    float* xr = x + (long)r * CC;
    const unsigned short* pr = p + (long)r * CC;
    float v[3];
#pragma unroll
    for (int i = 0; i < 3; ++i) {
        int c = tid + i * 256;
        float s = xr[c] + bias[c];
        s += b2f(pr[c]);
        s += b2f(pr[c + 1 * NX]);
        s += b2f(pr[c + 2 * NX]);
        s += b2f(pr[c + 3 * NX]);
        xr[c] = s;
        v[i] = s;
    }
    if (!DOLN) return;
    float s  = v[0] + v[1] + v[2];
    float sq = v[0]*v[0] + v[1]*v[1] + v[2]*v[2];
#pragma unroll
    for (int off = 32; off > 0; off >>= 1) {
        s  += __shfl_down(s, off);
        sq += __shfl_down(sq, off);
    }
    __shared__ float ss[4], ssq[4];
    int w = tid >> 6;
    if ((tid & 63) == 0) { ss[w] = s; ssq[w] = sq; }
    __syncthreads();
    s  = ss[0] + ss[1] + ss[2] + ss[3];
    sq = ssq[0] + ssq[1] + ssq[2] + ssq[3];
    float mean = s * (1.0f / CC);
    float var  = sq * (1.0f / CC) - mean * mean;
    float rs   = rsqrtf(var + 1e-5f);
    __hip_bfloat16* yr = y + (long)r * CC;
#pragma unroll
    for (int i = 0; i < 3; ++i) {
        int c = tid + i * 256;
        yr[c] = __float2bfloat16((v[i] - mean) * rs * g[c] + b[c]);
    }
}

// ------------------------------------------------- weight convert/transpose
// src fp32 [R][D] -> dst bf16 [D][R]; 64x64 tiles; grid (D/64, R/64, L)
__global__ __launch_bounds__(256) void cvtT_k(const float* __restrict__ src,
    __hip_bfloat16* __restrict__ dst, int R, int D, long sSrc, long sDst)
{
    src += (long)blockIdx.z * sSrc;
    dst += (long)blockIdx.z * sDst;
    __shared__ float t[64][65];
    int d0 = blockIdx.x * 64, r0 = blockIdx.y * 64;
    int tid = threadIdx.x;
#pragma unroll
    for (int i = 0; i < 4; ++i) {
        int flat = tid + i * 256;
        int r = flat >> 4, c4 = (flat & 15) * 4;
        float4 v = *(const float4*)&src[(long)(r0 + r) * D + d0 + c4];
        t[r][c4 + 0] = v.x; t[r][c4 + 1] = v.y;
        t[r][c4 + 2] = v.z; t[r][c4 + 3] = v.w;
    }
    __syncthreads();
#pragma unroll
    for (int i = 0; i < 4; ++i) {
        int flat = tid + i * 256;
        int n = flat >> 4, kq = (flat & 15) * 4;
        ushort4 o;
        o.x = f2b_bits(t[kq + 0][n]); o.y = f2b_bits(t[kq + 1][n]);
        o.z = f2b_bits(t[kq + 2][n]); o.w = f2b_bits(t[kq + 3][n]);
        *(ushort4*)&dst[(long)(d0 + n) * R + r0 + kq] = o;
    }
}

// Wq/Wk/Wv [L][h][768][64] -> qkvT_all [L][2304][768]; grid (12, 36, L)
__global__ __launch_bounds__(256) void cvt_qkvT(const float* __restrict__ Wq,
    const float* __restrict__ Wk, const float* __restrict__ Wv,
    __hip_bfloat16* __restrict__ out)
{
    int c0 = blockIdx.x * 64;
    int g  = blockIdx.y;
    int l  = blockIdx.z;
    int which = g / 12, h = g % 12;
    const long wAtt = (long)HH * CC * HSZ;
    const float* src = (which == 0 ? Wq : which == 1 ? Wk : Wv)
                       + l * wAtt + (long)h * CC * HSZ;   // [768][64]
    __hip_bfloat16* dst = out + (long)l * NQKV * CC + (long)(which * CC + h * HSZ) * CC;
    __shared__ float t[64][65];
    int tid = threadIdx.x;
#pragma unroll
    for (int i = 0; i < 4; ++i) {
        int flat = tid + i * 256;
        int r = flat >> 4, c4 = (flat & 15) * 4;
        float4 v = *(const float4*)&src[(long)(c0 + r) * HSZ + c4];
        t[r][c4 + 0] = v.x; t[r][c4 + 1] = v.y;
        t[r][c4 + 2] = v.z; t[r][c4 + 3] = v.w;
    }
    __syncthreads();
#pragma unroll
    for (int i = 0; i < 4; ++i) {
        int flat = tid + i * 256;
        int n = flat >> 4, kq = (flat & 15) * 4;
        ushort4 o;
        o.x = f2b_bits(t[kq + 0][n]); o.y = f2b_bits(t[kq + 1][n]);
        o.z = f2b_bits(t[kq + 2][n]); o.w = f2b_bits(t[kq + 3][n]);
        *(ushort4*)&dst[(long)n * CC + c0 + kq] = o;
    }
}

// ---------------------------------------------------------------- bf16 MFMA GEMM
// C[M,N] = A[M,K] @ B[K,N]; A bf16 [M][lda], BT bf16 [N][ldb] (=B^T); K%32==0,
// K/32 >= 3. Tile 64 x 128, BK=32, 4 waves (2x2), each wave 32x64 out.
// Depth-4 pipeline: 4 LDS buffers, 3 tiles in flight via global_load_lds,
// counted s_waitcnt vmcnt(N) + raw s_barrier (never drains to 0 mid-loop).
// T1: bijective XCD swizzle of (bx,by) within each z-slice (slice % 8 == 0).
// T2: source column-block rotation kills the 8-way LDS bank conflict.
// EPI 1: QKV (cols<1536 -> Cb, cols>=1536 -> Vt transposed);
// EPI 2: +bias exact-GELU -> bf16;
// EPI 5: split-K over blockIdx.z: store bf16 partial to Cb + sk*NX (no bias).
template <int EPI>
__global__ __launch_bounds__(256, 3) void gemm_bf16(
    const __hip_bfloat16* __restrict__ A,
    const __hip_bfloat16* __restrict__ BT,
    __hip_bfloat16* __restrict__ Cb, float* __restrict__ Cf,
    const float* __restrict__ bias, __hip_bfloat16* __restrict__ Vt,
    int K, int lda, int ldb, int ldc)
{
    __shared__ short Asm[4][64 * 32];
    __shared__ short Bsm[4][128 * 32];
    const int tid  = threadIdx.x;
    const int lane = tid & 63;
    const int wid  = tid >> 6;
    const int wm = wid >> 1, wn = wid & 1;

    // T1 XCD swizzle: hardware block (x,y) computes logical tile swz
    const int gx = gridDim.x;
    const int slice = gx * gridDim.y;            // divisible by 8
    int flat = blockIdx.y * gx + blockIdx.x;
    int swz  = (flat & 7) * (slice >> 3) + (flat >> 3);
    const int row0 = (swz / gx) * 64, col0 = (swz % gx) * 128;
    const int sk = (EPI == 5) ? blockIdx.z : 0;

    const int gr = tid >> 2;               // staging row 0..63
    // swizzled source column-block: cb = (pos + (row>>1)) & 3
    const int cb = ((tid & 3) + (tid >> 3)) & 3;
    const int gk = cb * 8;                 // k offset in shorts
    const __hip_bfloat16* Ap = A  + (long)(row0 + gr) * lda + sk * K + gk;
    const __hip_bfloat16* Bp = BT + (long)(col0 + gr) * ldb + sk * K + gk;
    const int lofs = wid * 512;            // per-wave LDS segment (shorts)

    f32x4 acc[2][4] = {};
    const int fr = lane & 15, g = lane >> 4;

    // swizzled read offsets (shorts), fixed per lane: row*32 + ((g-(row>>1))&3)*8
    int offA[2], offB[4];
#pragma unroll
    for (int m = 0; m < 2; ++m) {
        int row = wm * 32 + m * 16 + fr;
        offA[m] = row * 32 + (((g - (row >> 1)) & 3) * 8);
    }
#pragma unroll
    for (int n = 0; n < 4; ++n) {
        int row = wn * 64 + n * 16 + fr;
        offB[n] = row * 32 + (((g - (row >> 1)) & 3) * 8);
    }

#define STAGE(buf)                                                          \
    do {                                                                    \
        gl_lds16(Ap, &Asm[buf][lofs]);                                      \
        gl_lds16(Bp, &Bsm[buf][lofs]);                                      \
        gl_lds16(Bp + (long)64 * ldb, &Bsm[buf][lofs + 64 * 32]);           \
        Ap += 32; Bp += 32;                                                 \
    } while (0)

    // prologue: tiles 0,1,2 in flight (3 loads each)
    STAGE(0); STAGE(1); STAGE(2);

    const int nt = K >> 5;                 // >= 3
    for (int t = 0; t < nt; ++t) {
        if (t < nt - 2)       asm volatile("s_waitcnt vmcnt(6)" ::: "memory");
        else if (t == nt - 2) asm volatile("s_waitcnt vmcnt(3)" ::: "memory");
        else                  asm volatile("s_waitcnt vmcnt(0)" ::: "memory");
        __builtin_amdgcn_s_barrier();      // all waves' tile-t loads resident;
        __builtin_amdgcn_sched_barrier(0); // also fences reuse of buf[(t+3)&3]
        if (t + 3 < nt) STAGE((t + 3) & 3);

        const int cur = t & 3;
        short8 af[2], bf[4];
#pragma unroll
        for (int m = 0; m < 2; ++m)
            af[m] = *(const short8*)&Asm[cur][offA[m]];
#pragma unroll
        for (int n = 0; n < 4; ++n)
            bf[n] = *(const short8*)&Bsm[cur][offB[n]];
#pragma unroll
        for (int m = 0; m < 2; ++m)
#pragma unroll
            for (int n = 0; n < 4; ++n)
                acc[m][n] = __builtin_amdgcn_mfma_f32_16x16x32_bf16(
                    af[m], bf[n], acc[m][n], 0, 0, 0);
    }
#undef STAGE

    const int fq = lane >> 4;
#pragma unroll
    for (int m = 0; m < 2; ++m) {
        int rbase = row0 + wm * 32 + m * 16 + fq * 4;
#pragma unroll
        for (int n = 0; n < 4; ++n) {
            int col = col0 + wn * 64 + n * 16 + fr;
            if (EPI == 1 && col >= 1536) {
                int hd = col - 1536;
                int b = rbase >> 9, t = rbase & (TT - 1);
                ushort4 o;
                o.x = f2b_bits(acc[m][n][0]); o.y = f2b_bits(acc[m][n][1]);
                o.z = f2b_bits(acc[m][n][2]); o.w = f2b_bits(acc[m][n][3]);
                *(ushort4*)&Vt[((long)(b * HH + (hd >> 6)) * HSZ + (hd & 63)) * TT + t] = o;
                continue;
            }
            float bv = (EPI == 2) ? bias[col] : 0.f;
#pragma unroll
            for (int j = 0; j < 4; ++j) {
                long row = rbase + j;
                float v = acc[m][n][j];
                if (EPI == 1) {
                    Cb[row * ldc + col] = __float2bfloat16(v);
                } else if (EPI == 2) {
                    v += bv;
                    v = 0.5f * v * (1.0f + erff(v * 0.70710678118654752f));
                    Cb[row * ldc + col] = __float2bfloat16(v);
                } else { // EPI == 5: bf16 partial
                    Cb[(long)sk * NX + row * ldc + col] = __float2bfloat16(v);
                }
            }
        }
    }
}

// ---------------------------------------------------------------- MFMA flash attention
// qkv [2048][2304] bf16 (q|k cols used), vT [B][H][64][512] bf16.
// One wave per block -> NO __syncthreads (it would drain vmcnt and kill the
// K/V register prefetch); intra-wave LDS ordering via compiler lgkmcnt +
// sched_barrier(0). T1 XCD swizzle keeps whole (b,h) K/V streams per XCD.
__global__ __launch_bounds__(64) void attn_mfma(
    const __hip_bfloat16* __restrict__ qkv,
    const __hip_bfloat16* __restrict__ vT,
    __hip_bfloat16* __restrict__ o)
{
    int flat = blockIdx.x + 32 * (blockIdx.y + 12 * blockIdx.z);
    int swz  = (flat & 7) * 192 + (flat >> 3);     // 1536 blocks, 8 XCDs
    const int qt = swz & 31;
    const int h  = (swz >> 5) % 12;
    const int b  = swz / 384;
    const int lane = threadIdx.x;
    const int t0 = qt * 16;
    const int fr = lane & 15, g = lane >> 4;

    __shared__ unsigned short P_lds[16 * 40];
    __shared__ float corr_lds[16], l_lds[16];

    const long qbase = ((long)(b * TT + t0 + fr)) * NQKV + h * HSZ + g * 8;
    short8 qf0 = *(const short8*)(qkv + qbase);
    short8 qf1 = *(const short8*)(qkv + qbase + 32);

    f32x4 oacc[4] = {};
    float m_run = -3.0e38f, l_run = 0.f;
    const int t_lane = t0 + fr;
    const int smax = t0 + 15;
    const long kcol = CC + h * HSZ + g * 8;
    const long vrow = (((long)(b * HH + h) * HSZ) + fr) * TT + g * 8;

    // preload K chunk 0 (rows fr, 16+fr)
    short8 ka0, ka1, ka2, ka3;
    {
        long kb0 = ((long)(b * TT + fr)) * NQKV + kcol;
        long kb1 = ((long)(b * TT + 16 + fr)) * NQKV + kcol;
        ka0 = *(const short8*)(qkv + kb0);
        ka1 = *(const short8*)(qkv + kb0 + 32);
        ka2 = *(const short8*)(qkv + kb1);
        ka3 = *(const short8*)(qkv + kb1 + 32);
    }

    for (int s0 = 0; s0 <= smax; s0 += 32) {
        // S^T for two 16-key subtiles from registers
        f32x4 st0 = {}, st1 = {};
        st0 = __builtin_amdgcn_mfma_f32_16x16x32_bf16(ka0, qf0, st0, 0, 0, 0);
        st0 = __builtin_amdgcn_mfma_f32_16x16x32_bf16(ka1, qf1, st0, 0, 0, 0);
        st1 = __builtin_amdgcn_mfma_f32_16x16x32_bf16(ka2, qf0, st1, 0, 0, 0);
        st1 = __builtin_amdgcn_mfma_f32_16x16x32_bf16(ka3, qf1, st1, 0, 0, 0);

        // prefetch next K chunk (regs) — lands during softmax
        const bool more = (s0 + 32 <= smax);
        short8 kn0, kn1, kn2, kn3;
        if (more) {
            long kb0 = ((long)(b * TT + s0 + 32 + fr)) * NQKV + kcol;
            long kb1 = ((long)(b * TT + s0 + 48 + fr)) * NQKV + kcol;
            kn0 = *(const short8*)(qkv + kb0);
            kn1 = *(const short8*)(qkv + kb0 + 32);
            kn2 = *(const short8*)(qkv + kb1);
            kn3 = *(const short8*)(qkv + kb1 + 32);
        }
        // prefetch V chunk (regs) — lands during softmax/pack
        short8 vc0 = *(const short8*)(vT + vrow + s0);
        short8 vc1 = *(const short8*)(vT + vrow + 16 * TT + s0);
        short8 vc2 = *(const short8*)(vT + vrow + 32 * TT + s0);
        short8 vc3 = *(const short8*)(vT + vrow + 48 * TT + s0);

        // scale + causal mask + online softmax stats (q = fr, lane-local)
        float p[8];
        float mx = -3.0e38f;
#pragma unroll
        for (int j = 0; j < 4; ++j) {
            int s = s0 + g * 4 + j;
            float v = st0[j] * 0.125f;
            v = (s <= t_lane) ? v : -3.0e38f;
            p[j] = v; mx = fmaxf(mx, v);
        }
#pragma unroll
        for (int j = 0; j < 4; ++j) {
            int s = s0 + 16 + g * 4 + j;
            float v = st1[j] * 0.125f;
            v = (s <= t_lane) ? v : -3.0e38f;
            p[4 + j] = v; mx = fmaxf(mx, v);
        }
        mx = fmaxf(mx, __shfl_xor(mx, 16));
        mx = fmaxf(mx, __shfl_xor(mx, 32));
        float mnew = fmaxf(m_run, mx);
        float corr = __expf(m_run - mnew);
        float psum = 0.f;
#pragma unroll
        for (int i = 0; i < 8; ++i) {
            float e = __expf(p[i] - mnew);
            p[i] = e; psum += e;
        }
        psum += __shfl_xor(psum, 16);
        psum += __shfl_xor(psum, 32);
        l_run = l_run * corr + psum;
        m_run = mnew;

        if (lane < 16) corr_lds[lane] = corr;
        unsigned u0 = (unsigned)f2b_bits(p[0]) | ((unsigned)f2b_bits(p[1]) << 16);
        unsigned u1 = (unsigned)f2b_bits(p[2]) | ((unsigned)f2b_bits(p[3]) << 16);
        unsigned u2 = (unsigned)f2b_bits(p[4]) | ((unsigned)f2b_bits(p[5]) << 16);
        unsigned u3 = (unsigned)f2b_bits(p[6]) | ((unsigned)f2b_bits(p[7]) << 16);
        *(unsigned*)&P_lds[fr * 40 + g * 4]          = u0;
        *(unsigned*)&P_lds[fr * 40 + g * 4 + 2]      = u1;
        *(unsigned*)&P_lds[fr * 40 + 16 + g * 4]     = u2;
        *(unsigned*)&P_lds[fr * 40 + 16 + g * 4 + 2] = u3;
        __builtin_amdgcn_sched_barrier(0);   // DS writes ordered before reads

        float cr0 = corr_lds[g * 4 + 0], cr1 = corr_lds[g * 4 + 1];
        float cr2 = corr_lds[g * 4 + 2], cr3 = corr_lds[g * 4 + 3];
        short8 pf = *(const short8*)&P_lds[fr * 40 + g * 8];
        oacc[0][0] *= cr0; oacc[0][1] *= cr1; oacc[0][2] *= cr2; oacc[0][3] *= cr3;
        oacc[0] = __builtin_amdgcn_mfma_f32_16x16x32_bf16(pf, vc0, oacc[0], 0, 0, 0);
        oacc[1][0] *= cr0; oacc[1][1] *= cr1; oacc[1][2] *= cr2; oacc[1][3] *= cr3;
        oacc[1] = __builtin_amdgcn_mfma_f32_16x16x32_bf16(pf, vc1, oacc[1], 0, 0, 0);
        oacc[2][0] *= cr0; oacc[2][1] *= cr1; oacc[2][2] *= cr2; oacc[2][3] *= cr3;
        oacc[2] = __builtin_amdgcn_mfma_f32_16x16x32_bf16(pf, vc2, oacc[2], 0, 0, 0);
        oacc[3][0] *= cr0; oacc[3][1] *= cr1; oacc[3][2] *= cr2; oacc[3][3] *= cr3;
        oacc[3] = __builtin_amdgcn_mfma_f32_16x16x32_bf16(pf, vc3, oacc[3], 0, 0, 0);

        if (more) { ka0 = kn0; ka1 = kn1; ka2 = kn2; ka3 = kn3; }
        __builtin_amdgcn_sched_barrier(0);   // WAR: P reads before next writes
    }

    if (lane < 16) l_lds[lane] = l_run;
    __builtin_amdgcn_sched_barrier(0);
    float il0 = 1.f / l_lds[g * 4 + 0], il1 = 1.f / l_lds[g * 4 + 1];
    float il2 = 1.f / l_lds[g * 4 + 2], il3 = 1.f / l_lds[g * 4 + 3];
#pragma unroll
    for (int dt = 0; dt < 4; ++dt) {
        long cbase = (long)(b * TT + t0) * CC + h * HSZ + dt * 16 + fr;
        o[cbase + (g * 4 + 0) * (long)CC] = __float2bfloat16(oacc[dt][0] * il0);
        o[cbase + (g * 4 + 1) * (long)CC] = __float2bfloat16(oacc[dt][1] * il1);
        o[cbase + (g * 4 + 2) * (long)CC] = __float2bfloat16(oacc[dt][2] * il2);
        o[cbase + (g * 4 + 3) * (long)CC] = __float2bfloat16(oacc[dt][3] * il3);
    }
}

// ---------------------------------------------------------------- final LN + head
__global__ __launch_bounds__(256) void head_k(const float* __restrict__ x,
    const float* __restrict__ g, const float* __restrict__ bb,
    const float* __restrict__ Wh, const float* __restrict__ bh,
    float* __restrict__ out)
{
    int r = blockIdx.x, tid = threadIdx.x;
    const float* xr = x + (long)r * CC;
    float v[3];
    v[0] = xr[tid]; v[1] = xr[tid + 256]; v[2] = xr[tid + 512];
    float s  = v[0] + v[1] + v[2];
    float sq = v[0]*v[0] + v[1]*v[1] + v[2]*v[2];
#pragma unroll
    for (int off = 32; off > 0; off >>= 1) {
        s  += __shfl_down(s, off);
        sq += __shfl_down(sq, off);
    }
    __shared__ float ss[4], ssq[4];
    int w = tid >> 6;
    if ((tid & 63) == 0) { ss[w] = s; ssq[w] = sq; }
    __syncthreads();
    s  = ss[0] + ss[1] + ss[2] + ss[3];
    sq = ssq[0] + ssq[1] + ssq[2] + ssq[3];
    float mean = s * (1.0f / CC);
    float var  = sq * (1.0f / CC) - mean * mean;
    float rs   = rsqrtf(var + 1e-5f);

    float acc[16];
#pragma unroll
    for (int j = 0; j < 16; ++j) acc[j] = 0.f;
#pragma unroll
    for (int i = 0; i < 3; ++i) {
        int c = tid + i * 256;
        float xnv = (v[i] - mean) * rs * g[c] + bb[c];
        const float* wr = Wh + (long)c * 16;
#pragma unroll
        for (int j = 0; j < 16; ++j) acc[j] = fmaf(xnv, wr[j], acc[j]);
    }
#pragma unroll
    for (int off = 32; off > 0; off >>= 1)
#pragma unroll
        for (int j = 0; j < 16; ++j) acc[j] += __shfl_down(acc[j], off);
    __shared__ float red[4][16];
    if ((tid & 63) == 0)
#pragma unroll
        for (int j = 0; j < 16; ++j) red[w][j] = acc[j];
    __syncthreads();
    if (tid < 16)
        out[(long)r * 16 + tid] =
            red[0][tid] + red[1][tid] + red[2][tid] + red[3][tid] + bh[tid];
}

// ---------------------------------------------------------------- launch
extern "C" void kernel_launch(void* const* d_in, const int* in_sizes, int n_in,
                              void* d_out, int out_size, void* d_ws, size_t ws_size,
                              hipStream_t stream)
{
    const int*   idx  = (const int*)  d_in[0];
    const float* tok  = (const float*)d_in[1];
    const float* pos  = (const float*)d_in[2];
    const float* Wq   = (const float*)d_in[3];
    const float* Wk   = (const float*)d_in[4];
    const float* Wv   = (const float*)d_in[5];
    const float* Wo   = (const float*)d_in[6];
    const float* bo   = (const float*)d_in[7];
    const float* W1   = (const float*)d_in[8];
    const float* b1   = (const float*)d_in[9];
    const float* W2   = (const float*)d_in[10];
    const float* b2   = (const float*)d_in[11];
    const float* ln1g = (const float*)d_in[12];
    const float* ln1b = (const float*)d_in[13];
    const float* ln2g = (const float*)d_in[14];
    const float* ln2b = (const float*)d_in[15];
    const float* lnfg = (const float*)d_in[16];
    const float* lnfb = (const float*)d_in[17];
    const float* Wh   = (const float*)d_in[18];
    const float* bh   = (const float*)d_in[19];

    char* w = (char*)d_ws;
    float*          x     = (float*)w;          w += NX * 4;
    __hip_bfloat16* xn_b  = (__hip_bfloat16*)w; w += NX * 2;
    __hip_bfloat16* qkvb  = (__hip_bfloat16*)w; w += (long)BTOT * NQKV * 2;
    __hip_bfloat16* vT    = (__hip_bfloat16*)w; w += NX * 2;
    __hip_bfloat16* o_b   = (__hip_bfloat16*)w; w += NX * 2;
    __hip_bfloat16* hb    = (__hip_bfloat16*)w; w += (long)BTOT * C4 * 2;
    __hip_bfloat16* qkvT  = (__hip_bfloat16*)w; w += (long)LL * NQKV * CC * 2;
    __hip_bfloat16* woT   = (__hip_bfloat16*)w; w += (long)LL * CC * CC * 2;
    __hip_bfloat16* w1T   = (__hip_bfloat16*)w; w += (long)LL * C4 * CC * 2;
    __hip_bfloat16* w2T   = (__hip_bfloat16*)w; w += (long)LL * CC * C4 * 2;
    __hip_bfloat16* pbuf  = (__hip_bfloat16*)w; w += 4 * NX * 2;

    // ---- all weight conversions upfront (4 launches) ----
    cvt_qkvT<<<dim3(12, 36, LL), 256, 0, stream>>>(Wq, Wk, Wv, qkvT);
    cvtT_k<<<dim3(12, 12, LL), 256, 0, stream>>>(Wo, woT, CC, CC,
        (long)CC * CC, (long)CC * CC);
    cvtT_k<<<dim3(48, 12, LL), 256, 0, stream>>>(W1, w1T, CC, C4,
        (long)CC * C4, (long)CC * C4);
    cvtT_k<<<dim3(12, 48, LL), 256, 0, stream>>>(W2, w2T, C4, CC,
        (long)C4 * CC, (long)C4 * CC);

    embed_k<<<BTOT, 256, 0, stream>>>(idx, tok, pos, x);
    ln_b<<<BTOT, 256, 0, stream>>>(x, ln1g, ln1b, xn_b);   // layer-0 LN1

    for (int l = 0; l < LL; ++l) {
        // QKV: M=2048, N=2304, K=768; 576 blocks
        gemm_bf16<1><<<dim3(NQKV / 128, BTOT / 64), 256, 0, stream>>>(
            xn_b, qkvT + (long)l * NQKV * CC, qkvb, nullptr, nullptr, vT,
            CC, CC, CC, NQKV);

        attn_mfma<<<dim3(TT / 16, HH, 4), 64, 0, stream>>>(qkvb, vT, o_b);

        // proj: M=2048, N=768, K=768 split 4x192 -> bf16 partials; 768 blocks
        gemm_bf16<5><<<dim3(CC / 128, BTOT / 64, 4), 256, 0, stream>>>(
            o_b, woT + (long)l * CC * CC, pbuf, nullptr, nullptr, nullptr,
            192, CC, CC, CC);

        // x += sum(partials) + bo; xn = LN2(x)
        red_ln<true><<<BTOT, 256, 0, stream>>>(x, (const unsigned short*)pbuf,
            bo + l * CC, ln2g + l * CC, ln2b + l * CC, xn_b);

        // MLP1: M=2048, N=3072, K=768; 768 blocks
        gemm_bf16<2><<<dim3(C4 / 128, BTOT / 64), 256, 0, stream>>>(
            xn_b, w1T + (long)l * C4 * CC, hb, nullptr, b1 + l * C4, nullptr,
            CC, CC, CC, C4);

        // MLP2: M=2048, N=768, K=3072 split 4x768 -> bf16 partials; 768 blocks
        gemm_bf16<5><<<dim3(CC / 128, BTOT / 64, 4), 256, 0, stream>>>(
            hb, w2T + (long)l * CC * C4, pbuf, nullptr, nullptr, nullptr,
            768, C4, C4, CC);

        // x += sum(partials) + b2; xn = LN1(next layer) (skip LN on last)
        if (l < LL - 1) {
            red_ln<true><<<BTOT, 256, 0, stream>>>(x, (const unsigned short*)pbuf,
                b2 + l * CC, ln1g + (l + 1) * CC, ln1b + (l + 1) * CC, xn_b);
        } else {
            red_ln<false><<<BTOT, 256, 0, stream>>>(x, (const unsigned short*)pbuf,
                b2 + l * CC, nullptr, nullptr, nullptr);
        }
    }

    head_k<<<BTOT, 256, 0, stream>>>(x, lnfg, lnfb, Wh, bh, (float*)d_out);
}